// Round 6
// baseline (337.225 us; speedup 1.0000x reference)
//
#include <hip/hip_runtime.h>

#define T_STEPS 1024
#define B_DIM   128
#define D_DIM   256
#define H_DIM   256
#define DH      512   // D + H
#define INV2PI  0.15915494309189535f

// tanh(x) Pade(5,4): x(x^4+105x^2+945)/(15x^4+420x^2+945); err<1e-4 for |x|<=2.3.
// |c| provably <= 2.08 (fixed point of f*c+i*g with f,i<=0.731, g<=0.762).
__device__ __forceinline__ float tanh_pade(float x) {
    float t = x * x;
    float n = fmaf(t, t + 105.0f, 945.0f);
    float d = fmaf(t, fmaf(t, 15.0f, 420.0f), 945.0f);
    return x * n * __builtin_amdgcn_rcpf(d);
}

// quad_perm broadcast of role K within each 4-lane group (VALU DPP, no LDS).
template <int K>
__device__ __forceinline__ float quad_bcast(float v) {
    int r = __builtin_amdgcn_mov_dpp(__builtin_bit_cast(int, v), K * 0x55, 0xF, 0xF, true);
    return __builtin_bit_cast(float, r);
}

// xdot[row][k] = (x[row,:] . W[k,:256] + b[k]) * 1/(2*pi)  — pre-scaled to
// revolutions so k_scan can feed v_sin_f32 directly. Wave per row, grid-stride.
// Transpose-reduce: 7 shuffles/row instead of 24 (4 independent butterflies).
__global__ __launch_bounds__(256) void k_xdot(const float* __restrict__ x,
                                              const float* __restrict__ W,
                                              const float* __restrict__ bias,
                                              float* __restrict__ xdot) {
    const int lane = threadIdx.x & 63;
    const int wid = blockIdx.x * (blockDim.x >> 6) + (threadIdx.x >> 6);
    const int nw = (gridDim.x * blockDim.x) >> 6;
    const int nrows = T_STEPS * B_DIM;

    float4 wk0 = ((const float4*)(W + 0 * DH))[lane];
    float4 wk1 = ((const float4*)(W + 1 * DH))[lane];
    float4 wk2 = ((const float4*)(W + 2 * DH))[lane];
    float4 wk3 = ((const float4*)(W + 3 * DH))[lane];
    const float bl = bias[lane & 3];   // bias for the gate this lane will own

    const float4* xv4 = (const float4*)x;  // 64 float4 per row

    const bool b0 = (lane & 1) != 0;
    const bool b1 = (lane & 2) != 0;

    int row = wid;
    if (row >= nrows) return;
    float4 xv = xv4[row * 64 + lane];
    for (; row < nrows; row += nw) {
        float4 cur = xv;
        int nrow = row + nw;
        if (nrow < nrows) xv = xv4[nrow * 64 + lane];  // prefetch next row

        float p0 = fmaf(cur.x, wk0.x, fmaf(cur.y, wk0.y, fmaf(cur.z, wk0.z, cur.w * wk0.w)));
        float p1 = fmaf(cur.x, wk1.x, fmaf(cur.y, wk1.y, fmaf(cur.z, wk1.z, cur.w * wk1.w)));
        float p2 = fmaf(cur.x, wk2.x, fmaf(cur.y, wk2.y, fmaf(cur.z, wk2.z, cur.w * wk2.w)));
        float p3 = fmaf(cur.x, wk3.x, fmaf(cur.y, wk3.y, fmaf(cur.z, wk3.z, cur.w * wk3.w)));

        // stage 1: exchange across xor 1
        float sA = b0 ? p0 : p1;
        sA = __shfl_xor(sA, 1, 64);
        float A = (b0 ? p1 : p0) + sA;      // pair-sum of p_{bit0}
        float sB = b0 ? p2 : p3;
        sB = __shfl_xor(sB, 1, 64);
        float B = (b0 ? p3 : p2) + sB;      // pair-sum of p_{2+bit0}
        // stage 2: exchange across xor 2
        float s2 = b1 ? A : B;
        s2 = __shfl_xor(s2, 2, 64);
        float v = (b1 ? B : A) + s2;        // 4-lane-group sum of p_{lane&3}
        // stage 3: butterfly over the 16 groups
#pragma unroll
        for (int off = 4; off < 64; off <<= 1) v += __shfl_xor(v, off, 64);

        if (lane < 4) xdot[row * 4 + lane] = (v + bl) * INV2PI;
    }
}

// Sequential scan, 4 LANES PER CHAIN, register prefetch ring (r4 structure —
// LDS staging measured WORSE, r5: 94 vs 72.5 µs).
// NEW (r6): 1 block x 512 threads on ONE CU = 2 waves/SIMD. With 1 wave/SIMD
// (r4: 2 blocks x 256) the SIMD idles during the ~90cy dependency chain; a
// second resident wave interleaves issue into those stalls. Issue demand
// 2x~66cy < 2x chain, so wall/step ~= max(chain, issue) ~= 120-135 cy.
// Chain cuts: carry (tanhc, ov*wl) instead of h — next arg =
// fmaf(tanhc, ovwl, u) removes the h-mul from the recurrence cycle; Estrin
// gate poly. h itself is computed off the critical path for the store.
// NOTE: prefetch reads up to t=T_STEPS+15 — xdot backing (d_out) has
// >= (T_STEPS+16)*512 floats. Caller guarantees.
__global__ __launch_bounds__(512)
__attribute__((amdgpu_waves_per_eu(2, 2)))
void k_scan(const float* __restrict__ xdot,
            const float* __restrict__ W,
            float* __restrict__ hseq,
            float* __restrict__ cfin) {
    const int tid = threadIdx.x;      // 0..511
    const int r = tid & 3;            // gate role: f,i,g,o
    const int chain = tid >> 2;       // 0..127

    __shared__ float s_whp[4];
    {   // whp[k] = sum_h W[k, 256+h]; 32-thread groups, redundant across 512 ok
        int k = (tid >> 5) & 3, j = tid & 31;
        const float4* wr = (const float4*)(W + k * DH + D_DIM + j * 8);
        float4 v0 = wr[0], v1 = wr[1];
        float s = (v0.x + v0.y) + (v0.z + v0.w) + (v1.x + v1.y) + (v1.z + v1.w);
#pragma unroll
        for (int off = 16; off > 0; off >>= 1) s += __shfl_xor(s, off, 32);
        if (j == 0) s_whp[k] = s;
    }
    __syncthreads();
    const float wl = s_whp[r] * INV2PI;   // REVOLUTIONS: matches xdot scaling

    const bool isg = (r == 2);
    const float B0 = isg ? 0.0f       : 0.5f;
    const float B1 = isg ? 0.999904f  : 0.25f;
    const float B3 = isg ? -0.331065f : -1.0f / 48.0f;
    const float B5 = isg ? 0.120472f  : 1.0f / 480.0f;
    const float B7 = isg ? -0.027717f : -17.0f / 80640.0f;

    // prefetch ring: one gate scalar per lane per step; xdot[t*512 + tid] is
    // perfectly coalesced (256B per wave per step).
    float ring[16];
#pragma unroll
    for (int p = 0; p < 16; ++p) ring[p] = xdot[p * 512 + tid];

    float c = 0.0f;
    float tanhc = 0.0f;    // tanh(c) carried instead of h
    float ovwl = 0.0f;     // o * wl carried; a = tanhc*ovwl + u
    float4 h4;
    float4* hout4 = (float4*)(hseq + chain * T_STEPS);  // [b][t] layout
    for (int tb = 0; tb < T_STEPS; tb += 16) {
#pragma unroll
        for (int j = 0; j < 16; ++j) {          // j is compile-time constant
            float cur = ring[j];
            ring[j] = xdot[(tb + 16 + j) * 512 + tid];   // 16 steps ahead

            // a_r = h*w_r + u_r, with h*w_r = tanhc * (o*w_r)
            float sn = __builtin_amdgcn_sinf(fmaf(tanhc, ovwl, cur));
            // Estrin: gate = B0 + sn*(B1 + B3 t + B5 t^2 + B7 t^3), t = sn^2
            float t = sn * sn;
            float t2 = t * t;
            float e0 = fmaf(t, B3, B1);
            float e1 = fmaf(t, B7, B5);
            float p = fmaf(t2, e1, e0);
            float gate = fmaf(sn, p, B0);       // f/i/o: sigmoid; g: tanh

            float fv = quad_bcast<0>(gate);
            float iv = quad_bcast<1>(gate);
            float gv = quad_bcast<2>(gate);
            float ov = quad_bcast<3>(gate);

            c = fmaf(fv, c, iv * gv);
            ovwl = ov * wl;                     // off critical path
            tanhc = tanh_pade(c);               // the long pole
            float h = ov * tanhc;               // off critical path (store only)

            if ((j & 3) == 0)      h4.x = h;
            else if ((j & 3) == 1) h4.y = h;
            else if ((j & 3) == 2) h4.z = h;
            else { h4.w = h; if (r == 0) hout4[(tb + j) >> 2] = h4; }
        }
    }
    if (r == 0) cfin[chain] = c;
}

// broadcast h over H=256 columns; wave per output row of 64 float4s.
// rows: [0,131072) stacked, [131072,131200) hx, [131200,131328) cx
// hseq is [b][t]-major: value for output row r=(t*128+b) is hseq[b*1024 + t].
__global__ __launch_bounds__(256) void k_bcast(const float* __restrict__ hseq,
                                               const float* __restrict__ cfin,
                                               float4* __restrict__ out) {
    const int wave = blockIdx.x * (blockDim.x >> 6) + (threadIdx.x >> 6);
    const int lane = threadIdx.x & 63;
    const int NR = T_STEPS * B_DIM;
    if (wave >= NR + 2 * B_DIM) return;
    float v;
    if (wave < NR) {
        int t = wave >> 7, bb = wave & 127;
        v = hseq[bb * T_STEPS + t];
    } else if (wave < NR + B_DIM) {
        v = hseq[(wave - NR) * T_STEPS + (T_STEPS - 1)];
    } else {
        v = cfin[wave - NR - B_DIM];
    }
    out[(size_t)wave * 64 + lane] = make_float4(v, v, v, v);
}

extern "C" void kernel_launch(void* const* d_in, const int* in_sizes, int n_in,
                              void* d_out, int out_size, void* d_ws, size_t ws_size,
                              hipStream_t stream) {
    const float* x = (const float*)d_in[0];   // (1024,128,256) f32
    const float* W = (const float*)d_in[1];   // (4,512) f32
    const float* b = (const float*)d_in[2];   // (4,) f32
    // d_in[3] = qw — mathematically inert (sin invariant under RX then H)

    float* out = (float*)d_out;

    float* wsf  = (float*)d_ws;
    float* hseq = wsf + 16;                      // 131072 floats, [b][t]
    float* cfin = wsf + 16 + T_STEPS * B_DIM;    // 128 floats
    float* xdot = out;  // ~2.2 MB scratch in d_out head (incl. 16-step pad);
                        // d_out fully overwritten by k_bcast afterwards.

    k_xdot<<<2048, 256, 0, stream>>>(x, W, b, xdot);
    k_scan<<<1, 512, 0, stream>>>(xdot, W, hseq, cfin);

    const int rows = T_STEPS * B_DIM + 2 * B_DIM;          // 131328
    k_bcast<<<(rows + 3) / 4, 256, 0, stream>>>(hseq, cfin, (float4*)out);
}

// Round 8
// 295.104 us; speedup vs baseline: 1.1427x; 1.1427x over previous
//
#include <hip/hip_runtime.h>

#define T_STEPS 1024
#define B_DIM   128
#define D_DIM   256
#define H_DIM   256
#define DH      512   // D + H
#define INV2PI  0.15915494309189535f

// native vector type for nontemporal builtins (HIP float4 is a struct and
// is rejected by __builtin_nontemporal_*; ext_vector_type is accepted)
typedef float fx4 __attribute__((ext_vector_type(4)));

__device__ __forceinline__ float4 nt_load4(const float4* p) {
    fx4 v = __builtin_nontemporal_load((const fx4*)p);
    return *(float4*)&v;
}
__device__ __forceinline__ void nt_store4(float4* p, float4 v) {
    __builtin_nontemporal_store(*(fx4*)&v, (fx4*)p);
}

// tanh(x) Pade(5,4): x(x^4+105x^2+945)/(15x^4+420x^2+945); err<1e-4 for |x|<=2.3.
// |c| provably <= 2.08 (fixed point of f*c+i*g with f,i<=0.731, g<=0.762).
__device__ __forceinline__ float tanh_pade(float x) {
    float t = x * x;
    float n = fmaf(t, t + 105.0f, 945.0f);
    float d = fmaf(t, fmaf(t, 15.0f, 420.0f), 945.0f);
    return x * n * __builtin_amdgcn_rcpf(d);
}

// quad_perm broadcast of role K within each 4-lane group (VALU DPP, no LDS).
template <int K>
__device__ __forceinline__ float quad_bcast(float v) {
    int r = __builtin_amdgcn_mov_dpp(__builtin_bit_cast(int, v), K * 0x55, 0xF, 0xF, true);
    return __builtin_bit_cast(float, r);
}

// xdot[row][k] = (x[row,:] . W[k,:256] + b[k]) * 1/(2*pi)  — pre-scaled to
// revolutions so k_scan can feed v_sin_f32 directly. Wave per row, grid-stride.
// Transpose-reduce: 7 shuffles/row instead of 24 (4 independent butterflies).
// x is read-once (128 MiB): non-temporal loads to skip L2 pollution.
__global__ __launch_bounds__(256) void k_xdot(const float* __restrict__ x,
                                              const float* __restrict__ W,
                                              const float* __restrict__ bias,
                                              float* __restrict__ xdot) {
    const int lane = threadIdx.x & 63;
    const int wid = blockIdx.x * (blockDim.x >> 6) + (threadIdx.x >> 6);
    const int nw = (gridDim.x * blockDim.x) >> 6;
    const int nrows = T_STEPS * B_DIM;

    float4 wk0 = ((const float4*)(W + 0 * DH))[lane];
    float4 wk1 = ((const float4*)(W + 1 * DH))[lane];
    float4 wk2 = ((const float4*)(W + 2 * DH))[lane];
    float4 wk3 = ((const float4*)(W + 3 * DH))[lane];
    const float bl = bias[lane & 3];   // bias for the gate this lane will own

    const float4* xv4 = (const float4*)x;  // 64 float4 per row

    const bool b0 = (lane & 1) != 0;
    const bool b1 = (lane & 2) != 0;

    int row = wid;
    if (row >= nrows) return;
    float4 xv = nt_load4(&xv4[row * 64 + lane]);
    for (; row < nrows; row += nw) {
        float4 cur = xv;
        int nrow = row + nw;
        if (nrow < nrows) xv = nt_load4(&xv4[nrow * 64 + lane]);

        float p0 = fmaf(cur.x, wk0.x, fmaf(cur.y, wk0.y, fmaf(cur.z, wk0.z, cur.w * wk0.w)));
        float p1 = fmaf(cur.x, wk1.x, fmaf(cur.y, wk1.y, fmaf(cur.z, wk1.z, cur.w * wk1.w)));
        float p2 = fmaf(cur.x, wk2.x, fmaf(cur.y, wk2.y, fmaf(cur.z, wk2.z, cur.w * wk2.w)));
        float p3 = fmaf(cur.x, wk3.x, fmaf(cur.y, wk3.y, fmaf(cur.z, wk3.z, cur.w * wk3.w)));

        // stage 1: exchange across xor 1
        float sA = b0 ? p0 : p1;
        sA = __shfl_xor(sA, 1, 64);
        float A = (b0 ? p1 : p0) + sA;      // pair-sum of p_{bit0}
        float sB = b0 ? p2 : p3;
        sB = __shfl_xor(sB, 1, 64);
        float B = (b0 ? p3 : p2) + sB;      // pair-sum of p_{2+bit0}
        // stage 2: exchange across xor 2
        float s2 = b1 ? A : B;
        s2 = __shfl_xor(s2, 2, 64);
        float v = (b1 ? B : A) + s2;        // 4-lane-group sum of p_{lane&3}
        // stage 3: butterfly over the 16 groups
#pragma unroll
        for (int off = 4; off < 64; off <<= 1) v += __shfl_xor(v, off, 64);

        if (lane < 4) xdot[row * 4 + lane] = (v + bl) * INV2PI;
    }
}

// Sequential scan, 4 LANES PER CHAIN, register prefetch ring.
// CONFIG (measured): 2 blocks x 256 = 8 waves at 1 wave/SIMD over 2 CUs.
//   r4 (this config, old chain): scan 72.5 µs.
//   r5 (LDS staging):            94 µs  — reverted.
//   r6 (1 CU, 2 waves/SIMD):     101.7 µs — reverted. Interleaving raised
//   per-SIMD throughput (170->119 cy/chain-step) but halving CUs lost more.
// CHAIN (kept from r6): carry (tanhc, ov*wl) instead of h — next arg =
// fmaf(tanhc, ovwl, u) removes the h-mul from the recurrence cycle; Estrin
// gate poly. h computed off-path for the store only.
// NOTE: prefetch reads up to t=T_STEPS+15 — xdot backing (d_out) has
// >= (T_STEPS+16)*512 floats. Caller guarantees.
__global__ __launch_bounds__(256)
__attribute__((amdgpu_waves_per_eu(1, 1)))
void k_scan(const float* __restrict__ xdot,
            const float* __restrict__ W,
            float* __restrict__ hseq,
            float* __restrict__ cfin) {
    const int tid = blockIdx.x * 256 + threadIdx.x;   // 0..511
    const int r = tid & 3;            // gate role: f,i,g,o
    const int chain = tid >> 2;       // 0..127

    __shared__ float s_whp[4];
    {   // whp[k] = sum_h W[k, 256+h]; 32-thread groups, redundant writes ok
        int k = (threadIdx.x >> 5) & 3, j = threadIdx.x & 31;
        const float4* wr = (const float4*)(W + k * DH + D_DIM + j * 8);
        float4 v0 = wr[0], v1 = wr[1];
        float s = (v0.x + v0.y) + (v0.z + v0.w) + (v1.x + v1.y) + (v1.z + v1.w);
#pragma unroll
        for (int off = 16; off > 0; off >>= 1) s += __shfl_xor(s, off, 32);
        if (j == 0) s_whp[k] = s;
    }
    __syncthreads();
    const float wl = s_whp[r] * INV2PI;   // REVOLUTIONS: matches xdot scaling

    const bool isg = (r == 2);
    const float B0 = isg ? 0.0f       : 0.5f;
    const float B1 = isg ? 0.999904f  : 0.25f;
    const float B3 = isg ? -0.331065f : -1.0f / 48.0f;
    const float B5 = isg ? 0.120472f  : 1.0f / 480.0f;
    const float B7 = isg ? -0.027717f : -17.0f / 80640.0f;

    // prefetch ring: one gate scalar per lane per step; xdot[t*512 + tid] is
    // perfectly coalesced (256B per wave per step).
    float ring[16];
#pragma unroll
    for (int p = 0; p < 16; ++p) ring[p] = xdot[p * 512 + tid];

    float c = 0.0f;
    float tanhc = 0.0f;    // tanh(c) carried instead of h
    float ovwl = 0.0f;     // o * wl carried; a = tanhc*ovwl + u
    float4 h4;
    float4* hout4 = (float4*)(hseq + chain * T_STEPS);  // [b][t] layout
    for (int tb = 0; tb < T_STEPS; tb += 16) {
#pragma unroll
        for (int j = 0; j < 16; ++j) {          // j is compile-time constant
            float cur = ring[j];
            ring[j] = xdot[(tb + 16 + j) * 512 + tid];   // 16 steps ahead

            // a_r = h*w_r + u_r, with h*w_r = tanhc * (o*w_r)
            float sn = __builtin_amdgcn_sinf(fmaf(tanhc, ovwl, cur));
            // Estrin: gate = B0 + sn*(B1 + B3 t + B5 t^2 + B7 t^3), t = sn^2
            float t = sn * sn;
            float t2 = t * t;
            float e0 = fmaf(t, B3, B1);
            float e1 = fmaf(t, B7, B5);
            float p = fmaf(t2, e1, e0);
            float gate = fmaf(sn, p, B0);       // f/i/o: sigmoid; g: tanh

            float fv = quad_bcast<0>(gate);
            float iv = quad_bcast<1>(gate);
            float gv = quad_bcast<2>(gate);
            float ov = quad_bcast<3>(gate);

            c = fmaf(fv, c, iv * gv);
            ovwl = ov * wl;                     // off critical path
            tanhc = tanh_pade(c);               // the long pole
            float h = ov * tanhc;               // off critical path (store only)

            if ((j & 3) == 0)      h4.x = h;
            else if ((j & 3) == 1) h4.y = h;
            else if ((j & 3) == 2) h4.z = h;
            else { h4.w = h; if (r == 0) hout4[(tb + j) >> 2] = h4; }
        }
    }
    if (r == 0) cfin[chain] = c;
}

// broadcast h over H=256 columns; wave per output row of 64 float4s.
// rows: [0,131072) stacked, [131072,131200) hx, [131200,131328) cx
// hseq is [b][t]-major: value for output row r=(t*128+b) is hseq[b*1024 + t].
// Output is write-once 537 MB: non-temporal stores.
__global__ __launch_bounds__(256) void k_bcast(const float* __restrict__ hseq,
                                               const float* __restrict__ cfin,
                                               float4* __restrict__ out) {
    const int wave = blockIdx.x * (blockDim.x >> 6) + (threadIdx.x >> 6);
    const int lane = threadIdx.x & 63;
    const int NR = T_STEPS * B_DIM;
    if (wave >= NR + 2 * B_DIM) return;
    float v;
    if (wave < NR) {
        int t = wave >> 7, bb = wave & 127;
        v = hseq[bb * T_STEPS + t];
    } else if (wave < NR + B_DIM) {
        v = hseq[(wave - NR) * T_STEPS + (T_STEPS - 1)];
    } else {
        v = cfin[wave - NR - B_DIM];
    }
    nt_store4(&out[(size_t)wave * 64 + lane], make_float4(v, v, v, v));
}

extern "C" void kernel_launch(void* const* d_in, const int* in_sizes, int n_in,
                              void* d_out, int out_size, void* d_ws, size_t ws_size,
                              hipStream_t stream) {
    const float* x = (const float*)d_in[0];   // (1024,128,256) f32
    const float* W = (const float*)d_in[1];   // (4,512) f32
    const float* b = (const float*)d_in[2];   // (4,) f32
    // d_in[3] = qw — mathematically inert (sin invariant under RX then H)

    float* out = (float*)d_out;

    float* wsf  = (float*)d_ws;
    float* hseq = wsf + 16;                      // 131072 floats, [b][t]
    float* cfin = wsf + 16 + T_STEPS * B_DIM;    // 128 floats
    float* xdot = out;  // ~2.2 MB scratch in d_out head (incl. 16-step pad);
                        // d_out fully overwritten by k_bcast afterwards.

    k_xdot<<<2048, 256, 0, stream>>>(x, W, b, xdot);
    k_scan<<<2, 256, 0, stream>>>(xdot, W, hseq, cfin);

    const int rows = T_STEPS * B_DIM + 2 * B_DIM;          // 131328
    k_bcast<<<(rows + 3) / 4, 256, 0, stream>>>(hseq, cfin, (float4*)out);
}

// Round 9
// 290.971 us; speedup vs baseline: 1.1590x; 1.0142x over previous
//
#include <hip/hip_runtime.h>

#define T_STEPS 1024
#define B_DIM   128
#define D_DIM   256
#define H_DIM   256
#define DH      512   // D + H
#define INV2PI  0.15915494309189535f

// native vector type for nontemporal builtins (HIP float4 is a struct and
// is rejected by __builtin_nontemporal_*; ext_vector_type is accepted)
typedef float fx4 __attribute__((ext_vector_type(4)));

__device__ __forceinline__ float4 nt_load4(const float4* p) {
    fx4 v = __builtin_nontemporal_load((const fx4*)p);
    return *(float4*)&v;
}
__device__ __forceinline__ void nt_store4(float4* p, float4 v) {
    __builtin_nontemporal_store(*(fx4*)&v, (fx4*)p);
}

// quad_perm broadcast of role K within each 4-lane group (VALU DPP, no LDS).
template <int K>
__device__ __forceinline__ float quad_bcast(float v) {
    int r = __builtin_amdgcn_mov_dpp(__builtin_bit_cast(int, v), K * 0x55, 0xF, 0xF, true);
    return __builtin_bit_cast(float, r);
}

// xdot[row][k] = (x[row,:] . W[k,:256] + b[k]) * 1/(2*pi)  — pre-scaled to
// revolutions so k_scan can feed v_sin_f32 directly. Wave per row, grid-stride.
// Transpose-reduce: 7 shuffles/row instead of 24 (4 independent butterflies).
// x is read-once (128 MiB): non-temporal loads to skip L2 pollution.
__global__ __launch_bounds__(256) void k_xdot(const float* __restrict__ x,
                                              const float* __restrict__ W,
                                              const float* __restrict__ bias,
                                              float* __restrict__ xdot) {
    const int lane = threadIdx.x & 63;
    const int wid = blockIdx.x * (blockDim.x >> 6) + (threadIdx.x >> 6);
    const int nw = (gridDim.x * blockDim.x) >> 6;
    const int nrows = T_STEPS * B_DIM;

    float4 wk0 = ((const float4*)(W + 0 * DH))[lane];
    float4 wk1 = ((const float4*)(W + 1 * DH))[lane];
    float4 wk2 = ((const float4*)(W + 2 * DH))[lane];
    float4 wk3 = ((const float4*)(W + 3 * DH))[lane];
    const float bl = bias[lane & 3];   // bias for the gate this lane will own

    const float4* xv4 = (const float4*)x;  // 64 float4 per row

    const bool b0 = (lane & 1) != 0;
    const bool b1 = (lane & 2) != 0;

    int row = wid;
    if (row >= nrows) return;
    float4 xv = nt_load4(&xv4[row * 64 + lane]);
    for (; row < nrows; row += nw) {
        float4 cur = xv;
        int nrow = row + nw;
        if (nrow < nrows) xv = nt_load4(&xv4[nrow * 64 + lane]);

        float p0 = fmaf(cur.x, wk0.x, fmaf(cur.y, wk0.y, fmaf(cur.z, wk0.z, cur.w * wk0.w)));
        float p1 = fmaf(cur.x, wk1.x, fmaf(cur.y, wk1.y, fmaf(cur.z, wk1.z, cur.w * wk1.w)));
        float p2 = fmaf(cur.x, wk2.x, fmaf(cur.y, wk2.y, fmaf(cur.z, wk2.z, cur.w * wk2.w)));
        float p3 = fmaf(cur.x, wk3.x, fmaf(cur.y, wk3.y, fmaf(cur.z, wk3.z, cur.w * wk3.w)));

        // stage 1: exchange across xor 1
        float sA = b0 ? p0 : p1;
        sA = __shfl_xor(sA, 1, 64);
        float A = (b0 ? p1 : p0) + sA;      // pair-sum of p_{bit0}
        float sB = b0 ? p2 : p3;
        sB = __shfl_xor(sB, 1, 64);
        float B = (b0 ? p3 : p2) + sB;      // pair-sum of p_{2+bit0}
        // stage 2: exchange across xor 2
        float s2 = b1 ? A : B;
        s2 = __shfl_xor(s2, 2, 64);
        float v = (b1 ? B : A) + s2;        // 4-lane-group sum of p_{lane&3}
        // stage 3: butterfly over the 16 groups
#pragma unroll
        for (int off = 4; off < 64; off <<= 1) v += __shfl_xor(v, off, 64);

        if (lane < 4) xdot[row * 4 + lane] = (v + bl) * INV2PI;
    }
}

// Sequential scan, 4 LANES PER CHAIN, register prefetch ring.
// CONFIG (measured): 2 blocks x 256 = 8 waves at 1 wave/SIMD over 2 CUs.
//   r4: 72.5 µs | r5 LDS-staged: 94 (reverted) | r6 1-CU interleave: 101.7
//   (reverted) | r8 (chain cuts): ~73-79. Step is LATENCY-bound: wall ~=
//   dep-chain + issue, no overlap at 1 wave/SIMD.
// CHAIN (r9): tanh(c) deg-7 odd POLY (err<=5e-3 on |c|<=2.1) replaces
// Pade+rcp — chain 32->16 cy. Gate poly deg-5 depth-12 (sigmoid Taylor
// err 2.2e-4; g-lane fit err 7e-4 on [-1,1]). Total chain ~76->60 cy.
// Error budget: output threshold 0.0159, bf16 floor 0.0039; poly errors
// enter output as o*5e-3 ~= 3.6e-3 and feedback is damped (|2pi*ovwl|<=1.2,
// c-recurrence contractive f<=0.74) -> predicted absmax <= ~0.009.
// NOTE: prefetch reads up to t=T_STEPS+15 — xdot backing (d_out) has
// >= (T_STEPS+16)*512 floats. Caller guarantees.
__global__ __launch_bounds__(256)
__attribute__((amdgpu_waves_per_eu(1, 1)))
void k_scan(const float* __restrict__ xdot,
            const float* __restrict__ W,
            float* __restrict__ hseq,
            float* __restrict__ cfin) {
    const int tid = blockIdx.x * 256 + threadIdx.x;   // 0..511
    const int r = tid & 3;            // gate role: f,i,g,o
    const int chain = tid >> 2;       // 0..127

    __shared__ float s_whp[4];
    {   // whp[k] = sum_h W[k, 256+h]; 32-thread groups, redundant writes ok
        int k = (threadIdx.x >> 5) & 3, j = threadIdx.x & 31;
        const float4* wr = (const float4*)(W + k * DH + D_DIM + j * 8);
        float4 v0 = wr[0], v1 = wr[1];
        float s = (v0.x + v0.y) + (v0.z + v0.w) + (v1.x + v1.y) + (v1.z + v1.w);
#pragma unroll
        for (int off = 16; off > 0; off >>= 1) s += __shfl_xor(s, off, 32);
        if (j == 0) s_whp[k] = s;
    }
    __syncthreads();
    const float wl = s_whp[r] * INV2PI;   // REVOLUTIONS: matches xdot scaling

    // gate nonlinearity: one odd deg-5 poly, per-lane coeffs, depth 12:
    //   sigmoid(q) = 0.5 + q(1/4 - t/48 + t^2/480), t=q^2 (Taylor, err 2.2e-4)
    //   tanh(q)    = q(0.997948 - 0.310042 t + 0.073688 t^2) (fit, err<=7e-4)
    const bool isg = (r == 2);
    const float B0 = isg ? 0.0f       : 0.5f;
    const float B1 = isg ? 0.997948f  : 0.25f;
    const float B3 = isg ? -0.310042f : -1.0f / 48.0f;
    const float B5 = isg ? 0.073688f  : 1.0f / 480.0f;

    // tanh(c) deg-7 odd poly on |c|<=2.1 (Chebyshev-node fit, err<=5e-3):
    const float A1 = 0.9935504f, A3 = -0.2841420f,
                A5 = 0.0606190f, A7 = -0.00535853f;

    // prefetch ring: one gate scalar per lane per step; xdot[t*512 + tid] is
    // perfectly coalesced (256B per wave per step).
    float ring[16];
#pragma unroll
    for (int p = 0; p < 16; ++p) ring[p] = xdot[p * 512 + tid];

    float c = 0.0f;
    float tanhc = 0.0f;    // tanh(c) carried instead of h
    float ovwl = 0.0f;     // o * wl carried; a = tanhc*ovwl + u
    float4 h4;
    float4* hout4 = (float4*)(hseq + chain * T_STEPS);  // [b][t] layout
    for (int tb = 0; tb < T_STEPS; tb += 16) {
#pragma unroll
        for (int j = 0; j < 16; ++j) {          // j is compile-time constant
            float cur = ring[j];
            ring[j] = xdot[(tb + 16 + j) * 512 + tid];   // 16 steps ahead

            // a_r = h*w_r + u_r, with h*w_r = tanhc * (o*w_r)
            float sn = __builtin_amdgcn_sinf(fmaf(tanhc, ovwl, cur));
            // deg-5 depth-12: gate = (sn*t)*(B3 + B5 t) + (B0 + B1 sn)
            float t = sn * sn;
            float snt = sn * t;
            float q = fmaf(t, B5, B3);
            float r0 = fmaf(sn, B1, B0);
            float gate = fmaf(snt, q, r0);      // f/i/o: sigmoid; g: tanh

            float fv = quad_bcast<0>(gate);
            float iv = quad_bcast<1>(gate);
            float gv = quad_bcast<2>(gate);
            float ov = quad_bcast<3>(gate);

            c = fmaf(fv, c, iv * gv);
            ovwl = ov * wl;                     // off critical path
            // tanh(c) poly, depth 16: tc@4, ctc/s1@8, s@12, tanhc@16
            float tc  = c * c;
            float ctc = c * tc;
            float ac  = c * A1;
            float s1  = fmaf(tc, A7, A5);
            float s   = fmaf(tc, s1, A3);
            tanhc = fmaf(ctc, s, ac);
            float h = ov * tanhc;               // off critical path (store only)

            if ((j & 3) == 0)      h4.x = h;
            else if ((j & 3) == 1) h4.y = h;
            else if ((j & 3) == 2) h4.z = h;
            else { h4.w = h; if (r == 0) hout4[(tb + j) >> 2] = h4; }
        }
    }
    if (r == 0) cfin[chain] = c;
}

// broadcast h over H=256 columns; wave per output row of 64 float4s.
// rows: [0,131072) stacked, [131072,131200) hx, [131200,131328) cx
// hseq is [b][t]-major: value for output row r=(t*128+b) is hseq[b*1024 + t].
// Output is write-once: non-temporal stores.
__global__ __launch_bounds__(256) void k_bcast(const float* __restrict__ hseq,
                                               const float* __restrict__ cfin,
                                               float4* __restrict__ out) {
    const int wave = blockIdx.x * (blockDim.x >> 6) + (threadIdx.x >> 6);
    const int lane = threadIdx.x & 63;
    const int NR = T_STEPS * B_DIM;
    if (wave >= NR + 2 * B_DIM) return;
    float v;
    if (wave < NR) {
        int t = wave >> 7, bb = wave & 127;
        v = hseq[bb * T_STEPS + t];
    } else if (wave < NR + B_DIM) {
        v = hseq[(wave - NR) * T_STEPS + (T_STEPS - 1)];
    } else {
        v = cfin[wave - NR - B_DIM];
    }
    nt_store4(&out[(size_t)wave * 64 + lane], make_float4(v, v, v, v));
}

extern "C" void kernel_launch(void* const* d_in, const int* in_sizes, int n_in,
                              void* d_out, int out_size, void* d_ws, size_t ws_size,
                              hipStream_t stream) {
    const float* x = (const float*)d_in[0];   // (1024,128,256) f32
    const float* W = (const float*)d_in[1];   // (4,512) f32
    const float* b = (const float*)d_in[2];   // (4,) f32
    // d_in[3] = qw — mathematically inert (sin invariant under RX then H)

    float* out = (float*)d_out;

    float* wsf  = (float*)d_ws;
    float* hseq = wsf + 16;                      // 131072 floats, [b][t]
    float* cfin = wsf + 16 + T_STEPS * B_DIM;    // 128 floats
    float* xdot = out;  // ~2.2 MB scratch in d_out head (incl. 16-step pad);
                        // d_out fully overwritten by k_bcast afterwards.

    k_xdot<<<2048, 256, 0, stream>>>(x, W, b, xdot);
    k_scan<<<2, 256, 0, stream>>>(xdot, W, hseq, cfin);

    const int rows = T_STEPS * B_DIM + 2 * B_DIM;          // 131328
    k_bcast<<<(rows + 3) / 4, 256, 0, stream>>>(hseq, cfin, (float4*)out);
}

// Round 10
// 241.937 us; speedup vs baseline: 1.3939x; 1.2027x over previous
//
#include <hip/hip_runtime.h>

#define T_STEPS 1024
#define B_DIM   128
#define D_DIM   256
#define H_DIM   256
#define DH      512   // D + H
#define INV2PI  0.15915494309189535f
#define NSEG    8
#define SEGLEN  128   // T_STEPS / NSEG
#define WARMUP  128   // contraction warmup steps (segments 1..7)

// native vector type for nontemporal builtins (HIP float4 is a struct and
// is rejected by __builtin_nontemporal_*; ext_vector_type is accepted)
typedef float fx4 __attribute__((ext_vector_type(4)));

__device__ __forceinline__ float4 nt_load4(const float4* p) {
    fx4 v = __builtin_nontemporal_load((const fx4*)p);
    return *(float4*)&v;
}
__device__ __forceinline__ void nt_store4(float4* p, float4 v) {
    __builtin_nontemporal_store(*(fx4*)&v, (fx4*)p);
}

// quad_perm broadcast of role K within each 4-lane group (VALU DPP, no LDS).
template <int K>
__device__ __forceinline__ float quad_bcast(float v) {
    int r = __builtin_amdgcn_mov_dpp(__builtin_bit_cast(int, v), K * 0x55, 0xF, 0xF, true);
    return __builtin_bit_cast(float, r);
}

// xdot[row][k] = (x[row,:] . W[k,:256] + b[k]) * 1/(2*pi)  — pre-scaled to
// revolutions so k_scan can feed v_sin_f32 directly. Wave per row, grid-stride.
// Transpose-reduce: 7 shuffles/row instead of 24 (4 independent butterflies).
// x is read-once (128 MiB): non-temporal loads to skip L2 pollution.
__global__ __launch_bounds__(256) void k_xdot(const float* __restrict__ x,
                                              const float* __restrict__ W,
                                              const float* __restrict__ bias,
                                              float* __restrict__ xdot) {
    const int lane = threadIdx.x & 63;
    const int wid = blockIdx.x * (blockDim.x >> 6) + (threadIdx.x >> 6);
    const int nw = (gridDim.x * blockDim.x) >> 6;
    const int nrows = T_STEPS * B_DIM;

    float4 wk0 = ((const float4*)(W + 0 * DH))[lane];
    float4 wk1 = ((const float4*)(W + 1 * DH))[lane];
    float4 wk2 = ((const float4*)(W + 2 * DH))[lane];
    float4 wk3 = ((const float4*)(W + 3 * DH))[lane];
    const float bl = bias[lane & 3];   // bias for the gate this lane will own

    const float4* xv4 = (const float4*)x;  // 64 float4 per row

    const bool b0 = (lane & 1) != 0;
    const bool b1 = (lane & 2) != 0;

    int row = wid;
    if (row >= nrows) return;
    float4 xv = nt_load4(&xv4[row * 64 + lane]);
    for (; row < nrows; row += nw) {
        float4 cur = xv;
        int nrow = row + nw;
        if (nrow < nrows) xv = nt_load4(&xv4[nrow * 64 + lane]);

        float p0 = fmaf(cur.x, wk0.x, fmaf(cur.y, wk0.y, fmaf(cur.z, wk0.z, cur.w * wk0.w)));
        float p1 = fmaf(cur.x, wk1.x, fmaf(cur.y, wk1.y, fmaf(cur.z, wk1.z, cur.w * wk1.w)));
        float p2 = fmaf(cur.x, wk2.x, fmaf(cur.y, wk2.y, fmaf(cur.z, wk2.z, cur.w * wk2.w)));
        float p3 = fmaf(cur.x, wk3.x, fmaf(cur.y, wk3.y, fmaf(cur.z, wk3.z, cur.w * wk3.w)));

        // stage 1: exchange across xor 1
        float sA = b0 ? p0 : p1;
        sA = __shfl_xor(sA, 1, 64);
        float A = (b0 ? p1 : p0) + sA;      // pair-sum of p_{bit0}
        float sB = b0 ? p2 : p3;
        sB = __shfl_xor(sB, 1, 64);
        float B = (b0 ? p3 : p2) + sB;      // pair-sum of p_{2+bit0}
        // stage 2: exchange across xor 2
        float s2 = b1 ? A : B;
        s2 = __shfl_xor(s2, 2, 64);
        float v = (b1 ? B : A) + s2;        // 4-lane-group sum of p_{lane&3}
        // stage 3: butterfly over the 16 groups
#pragma unroll
        for (int off = 4; off < 64; off <<= 1) v += __shfl_xor(v, off, 64);

        if (lane < 4) xdot[row * 4 + lane] = (v + bl) * INV2PI;
    }
}

// SEGMENTED sequential scan, 4 LANES PER CHAIN, register prefetch ring.
// r10: T=1024 split into 8 segments of 128. Segment s>0 starts from ZERO
// state and runs 128 WARMUP steps (t in [128s-128,128s), no stores) before
// its 128 real steps. The recurrence is contractive (dc'/dc = f <= 0.73),
// so the wrong-start error decays ~lambda^128 -> invisible if lambda<~0.93.
// Segment 0's zero start is exact. 8x parallelism: 16 blocks x 256 thr
// = 64 waves at 1 wave/SIMD on 16 CUs; each wave runs 256 steps vs 1024.
// Per-step structure unchanged from r9 (latency-bound ~160 cy/step):
// tanh(c) deg-7 odd poly (err<=5e-3), deg-5 gate polys, carry (tanhc,ovwl).
// NOTE: prefetch reads up to t=T_STEPS+15 — xdot backing (d_out) has
// >= (T_STEPS+16)*512 floats. Caller guarantees.
__global__ __launch_bounds__(256)
__attribute__((amdgpu_waves_per_eu(1, 1)))
void k_scan(const float* __restrict__ xdot,
            const float* __restrict__ W,
            float* __restrict__ hseq,
            float* __restrict__ cfin) {
    const int seg  = blockIdx.x >> 1;                 // 0..7
    const int half = blockIdx.x & 1;                  // 64-chain group
    const int ltid = threadIdx.x;                     // 0..255
    const int r = ltid & 3;                           // gate role: f,i,g,o
    const int chain = half * 64 + (ltid >> 2);        // 0..127
    const int col = half * 256 + ltid;                // column in xdot row-512

    __shared__ float s_whp[4];
    {   // whp[k] = sum_h W[k, 256+h]; 32-thread groups, redundant writes ok
        int k = (ltid >> 5) & 3, j = ltid & 31;
        const float4* wr = (const float4*)(W + k * DH + D_DIM + j * 8);
        float4 v0 = wr[0], v1 = wr[1];
        float s = (v0.x + v0.y) + (v0.z + v0.w) + (v1.x + v1.y) + (v1.z + v1.w);
#pragma unroll
        for (int off = 16; off > 0; off >>= 1) s += __shfl_xor(s, off, 32);
        if (j == 0) s_whp[k] = s;
    }
    __syncthreads();
    const float wl = s_whp[r] * INV2PI;   // REVOLUTIONS: matches xdot scaling

    // gate nonlinearity: one odd deg-5 poly, per-lane coeffs, depth 12:
    //   sigmoid(q) = 0.5 + q(1/4 - t/48 + t^2/480), t=q^2 (Taylor, err 2.2e-4)
    //   tanh(q)    = q(0.997948 - 0.310042 t + 0.073688 t^2) (fit, err<=7e-4)
    const bool isg = (r == 2);
    const float B0 = isg ? 0.0f       : 0.5f;
    const float B1 = isg ? 0.997948f  : 0.25f;
    const float B3 = isg ? -0.310042f : -1.0f / 48.0f;
    const float B5 = isg ? 0.073688f  : 1.0f / 480.0f;

    // tanh(c) deg-7 odd poly on |c|<=2.1 (Chebyshev-node fit, err<=5e-3):
    const float A1 = 0.9935504f, A3 = -0.2841420f,
                A5 = 0.0606190f, A7 = -0.00535853f;

    const int tstart = seg * SEGLEN;                  // first stored t
    const int nwu = (seg == 0) ? 0 : WARMUP;          // warmup steps
    const int t0 = tstart - nwu;                      // first processed t

    // prefetch ring: one gate scalar per lane per step; coalesced 256B/wave.
    float ring[16];
#pragma unroll
    for (int p = 0; p < 16; ++p) ring[p] = xdot[(t0 + p) * 512 + col];

    float c = 0.0f;
    float tanhc = 0.0f;    // tanh(c) carried instead of h
    float ovwl = 0.0f;     // o * wl carried; a = tanhc*ovwl + u
    float4 h4;
    float4* hout4 = (float4*)(hseq + chain * T_STEPS);  // [b][t] layout

    // ---- warmup: converge state, no stores (block-uniform trip count) ----
    for (int tb = 0; tb < nwu; tb += 16) {
#pragma unroll
        for (int j = 0; j < 16; ++j) {
            float cur = ring[j];
            ring[j] = xdot[(t0 + tb + 16 + j) * 512 + col];

            float sn = __builtin_amdgcn_sinf(fmaf(tanhc, ovwl, cur));
            float t = sn * sn;
            float snt = sn * t;
            float q = fmaf(t, B5, B3);
            float r0 = fmaf(sn, B1, B0);
            float gate = fmaf(snt, q, r0);

            float fv = quad_bcast<0>(gate);
            float iv = quad_bcast<1>(gate);
            float gv = quad_bcast<2>(gate);
            float ov = quad_bcast<3>(gate);

            c = fmaf(fv, c, iv * gv);
            ovwl = ov * wl;
            float tc  = c * c;
            float ctc = c * tc;
            float ac  = c * A1;
            float s1  = fmaf(tc, A7, A5);
            float s   = fmaf(tc, s1, A3);
            tanhc = fmaf(ctc, s, ac);
        }
    }

    // ---- main: 128 stored steps; refill index continues seamlessly ----
    for (int tb = 0; tb < SEGLEN; tb += 16) {
#pragma unroll
        for (int j = 0; j < 16; ++j) {
            float cur = ring[j];
            ring[j] = xdot[(tstart + tb + 16 + j) * 512 + col];  // padded past end

            float sn = __builtin_amdgcn_sinf(fmaf(tanhc, ovwl, cur));
            float t = sn * sn;
            float snt = sn * t;
            float q = fmaf(t, B5, B3);
            float r0 = fmaf(sn, B1, B0);
            float gate = fmaf(snt, q, r0);

            float fv = quad_bcast<0>(gate);
            float iv = quad_bcast<1>(gate);
            float gv = quad_bcast<2>(gate);
            float ov = quad_bcast<3>(gate);

            c = fmaf(fv, c, iv * gv);
            ovwl = ov * wl;
            float tc  = c * c;
            float ctc = c * tc;
            float ac  = c * A1;
            float s1  = fmaf(tc, A7, A5);
            float s   = fmaf(tc, s1, A3);
            tanhc = fmaf(ctc, s, ac);
            float h = ov * tanhc;               // store only

            if ((j & 3) == 0)      h4.x = h;
            else if ((j & 3) == 1) h4.y = h;
            else if ((j & 3) == 2) h4.z = h;
            else { h4.w = h; if (r == 0) hout4[(tstart + tb + j) >> 2] = h4; }
        }
    }
    if (seg == NSEG - 1 && r == 0) cfin[chain] = c;
}

// broadcast h over H=256 columns; wave per output row of 64 float4s.
// rows: [0,131072) stacked, [131072,131200) hx, [131200,131328) cx
// hseq is [b][t]-major: value for output row r=(t*128+b) is hseq[b*1024 + t].
// Output is write-once: non-temporal stores.
__global__ __launch_bounds__(256) void k_bcast(const float* __restrict__ hseq,
                                               const float* __restrict__ cfin,
                                               float4* __restrict__ out) {
    const int wave = blockIdx.x * (blockDim.x >> 6) + (threadIdx.x >> 6);
    const int lane = threadIdx.x & 63;
    const int NR = T_STEPS * B_DIM;
    if (wave >= NR + 2 * B_DIM) return;
    float v;
    if (wave < NR) {
        int t = wave >> 7, bb = wave & 127;
        v = hseq[bb * T_STEPS + t];
    } else if (wave < NR + B_DIM) {
        v = hseq[(wave - NR) * T_STEPS + (T_STEPS - 1)];
    } else {
        v = cfin[wave - NR - B_DIM];
    }
    nt_store4(&out[(size_t)wave * 64 + lane], make_float4(v, v, v, v));
}

extern "C" void kernel_launch(void* const* d_in, const int* in_sizes, int n_in,
                              void* d_out, int out_size, void* d_ws, size_t ws_size,
                              hipStream_t stream) {
    const float* x = (const float*)d_in[0];   // (1024,128,256) f32
    const float* W = (const float*)d_in[1];   // (4,512) f32
    const float* b = (const float*)d_in[2];   // (4,) f32
    // d_in[3] = qw — mathematically inert (sin invariant under RX then H)

    float* out = (float*)d_out;

    float* wsf  = (float*)d_ws;
    float* hseq = wsf + 16;                      // 131072 floats, [b][t]
    float* cfin = wsf + 16 + T_STEPS * B_DIM;    // 128 floats
    float* xdot = out;  // ~2.2 MB scratch in d_out head (incl. 16-step pad);
                        // d_out fully overwritten by k_bcast afterwards.

    k_xdot<<<2048, 256, 0, stream>>>(x, W, b, xdot);
    k_scan<<<2 * NSEG, 256, 0, stream>>>(xdot, W, hseq, cfin);

    const int rows = T_STEPS * B_DIM + 2 * B_DIM;          // 131328
    k_bcast<<<(rows + 3) / 4, 256, 0, stream>>>(hseq, cfin, (float4*)out);
}

// Round 12
// 235.992 us; speedup vs baseline: 1.4290x; 1.0252x over previous
//
#include <hip/hip_runtime.h>

#define T_STEPS 1024
#define B_DIM   128
#define D_DIM   256
#define H_DIM   256
#define DH      512   // D + H
#define INV2PI  0.15915494309189535f
#define NSEG    16
#define SEGLEN  64    // T_STEPS / NSEG
#define WARMUP  96    // max contraction warmup steps (clamped to history)

// native vector type for nontemporal builtins (HIP float4 is a struct and
// is rejected by __builtin_nontemporal_*; ext_vector_type is accepted)
typedef float fx4 __attribute__((ext_vector_type(4)));

__device__ __forceinline__ float4 nt_load4(const float4* p) {
    fx4 v = __builtin_nontemporal_load((const fx4*)p);
    return *(float4*)&v;
}
__device__ __forceinline__ void nt_store4(float4* p, float4 v) {
    __builtin_nontemporal_store(*(fx4*)&v, (fx4*)p);
}

// quad_perm broadcast of role K within each 4-lane group (VALU DPP, no LDS).
template <int K>
__device__ __forceinline__ float quad_bcast(float v) {
    int r = __builtin_amdgcn_mov_dpp(__builtin_bit_cast(int, v), K * 0x55, 0xF, 0xF, true);
    return __builtin_bit_cast(float, r);
}

// xdot[row][k] = (x[row,:] . W[k,:256] + b[k]) * 1/(2*pi)  — pre-scaled to
// revolutions so k_scan can feed v_sin_f32 directly. Wave per row, grid-stride.
// Transpose-reduce: 7 shuffles/row instead of 24 (4 independent butterflies).
// x is read-once (128 MiB): non-temporal loads to skip L2 pollution.
__global__ __launch_bounds__(256) void k_xdot(const float* __restrict__ x,
                                              const float* __restrict__ W,
                                              const float* __restrict__ bias,
                                              float* __restrict__ xdot) {
    const int lane = threadIdx.x & 63;
    const int wid = blockIdx.x * (blockDim.x >> 6) + (threadIdx.x >> 6);
    const int nw = (gridDim.x * blockDim.x) >> 6;
    const int nrows = T_STEPS * B_DIM;

    float4 wk0 = ((const float4*)(W + 0 * DH))[lane];
    float4 wk1 = ((const float4*)(W + 1 * DH))[lane];
    float4 wk2 = ((const float4*)(W + 2 * DH))[lane];
    float4 wk3 = ((const float4*)(W + 3 * DH))[lane];
    const float bl = bias[lane & 3];   // bias for the gate this lane will own

    const float4* xv4 = (const float4*)x;  // 64 float4 per row

    const bool b0 = (lane & 1) != 0;
    const bool b1 = (lane & 2) != 0;

    int row = wid;
    if (row >= nrows) return;
    float4 xv = nt_load4(&xv4[row * 64 + lane]);
    for (; row < nrows; row += nw) {
        float4 cur = xv;
        int nrow = row + nw;
        if (nrow < nrows) xv = nt_load4(&xv4[nrow * 64 + lane]);

        float p0 = fmaf(cur.x, wk0.x, fmaf(cur.y, wk0.y, fmaf(cur.z, wk0.z, cur.w * wk0.w)));
        float p1 = fmaf(cur.x, wk1.x, fmaf(cur.y, wk1.y, fmaf(cur.z, wk1.z, cur.w * wk1.w)));
        float p2 = fmaf(cur.x, wk2.x, fmaf(cur.y, wk2.y, fmaf(cur.z, wk2.z, cur.w * wk2.w)));
        float p3 = fmaf(cur.x, wk3.x, fmaf(cur.y, wk3.y, fmaf(cur.z, wk3.z, cur.w * wk3.w)));

        // stage 1: exchange across xor 1
        float sA = b0 ? p0 : p1;
        sA = __shfl_xor(sA, 1, 64);
        float A = (b0 ? p1 : p0) + sA;      // pair-sum of p_{bit0}
        float sB = b0 ? p2 : p3;
        sB = __shfl_xor(sB, 1, 64);
        float B = (b0 ? p3 : p2) + sB;      // pair-sum of p_{2+bit0}
        // stage 2: exchange across xor 2
        float s2 = b1 ? A : B;
        s2 = __shfl_xor(s2, 2, 64);
        float v = (b1 ? B : A) + s2;        // 4-lane-group sum of p_{lane&3}
        // stage 3: butterfly over the 16 groups
#pragma unroll
        for (int off = 4; off < 64; off <<= 1) v += __shfl_xor(v, off, 64);

        if (lane < 4) xdot[row * 4 + lane] = (v + bl) * INV2PI;
    }
}

// SEGMENTED sequential scan, 4 LANES PER CHAIN, register prefetch ring.
// r10 (measured): NSEG=8/WARMUP=128 scan 68->~19 µs, absmax at bf16 floor
// => warmup error invisible => per-step contraction lambda < ~0.93.
// r11 CRASHED: SEGLEN=64 < WARMUP=96 made seg 1's t0 = 64-96 = -32 ->
// negative xdot index -> OOB read -> GPU fault. r12 FIX: clamp
// nwu = min(WARMUP, tstart). Bonus: segments whose warmup reaches t=0
// start from the TRUE zero state -> seg 1 (64 warmup from t=0) is EXACT.
// Segs >=2: 96 warmup, worst-case lambda^96 ~ 9e-4 -> absmax <= ~0.006
// (threshold 0.0159). 32 blocks x 256 thr = 1 wave/SIMD on 32 CUs; each
// wave runs <=160 steps vs r10's 256.
// Per-step structure (latency-bound ~160 cy/step): tanh(c) deg-7 odd poly
// (err<=5e-3), deg-5 gate polys, carry (tanhc,ovwl), DPP quad broadcasts.
// NOTE: prefetch reads up to t=T_STEPS+15 — xdot backing (d_out) has
// >= (T_STEPS+16)*512 floats. Caller guarantees.
__global__ __launch_bounds__(256)
__attribute__((amdgpu_waves_per_eu(1, 1)))
void k_scan(const float* __restrict__ xdot,
            const float* __restrict__ W,
            float* __restrict__ hseq,
            float* __restrict__ cfin) {
    const int seg  = blockIdx.x >> 1;                 // 0..15
    const int half = blockIdx.x & 1;                  // 64-chain group
    const int ltid = threadIdx.x;                     // 0..255
    const int r = ltid & 3;                           // gate role: f,i,g,o
    const int chain = half * 64 + (ltid >> 2);        // 0..127
    const int col = half * 256 + ltid;                // column in xdot row-512

    __shared__ float s_whp[4];
    {   // whp[k] = sum_h W[k, 256+h]; 32-thread groups, redundant writes ok
        int k = (ltid >> 5) & 3, j = ltid & 31;
        const float4* wr = (const float4*)(W + k * DH + D_DIM + j * 8);
        float4 v0 = wr[0], v1 = wr[1];
        float s = (v0.x + v0.y) + (v0.z + v0.w) + (v1.x + v1.y) + (v1.z + v1.w);
#pragma unroll
        for (int off = 16; off > 0; off >>= 1) s += __shfl_xor(s, off, 32);
        if (j == 0) s_whp[k] = s;
    }
    __syncthreads();
    const float wl = s_whp[r] * INV2PI;   // REVOLUTIONS: matches xdot scaling

    // gate nonlinearity: one odd deg-5 poly, per-lane coeffs, depth 12:
    //   sigmoid(q) = 0.5 + q(1/4 - t/48 + t^2/480), t=q^2 (Taylor, err 2.2e-4)
    //   tanh(q)    = q(0.997948 - 0.310042 t + 0.073688 t^2) (fit, err<=7e-4)
    const bool isg = (r == 2);
    const float B0 = isg ? 0.0f       : 0.5f;
    const float B1 = isg ? 0.997948f  : 0.25f;
    const float B3 = isg ? -0.310042f : -1.0f / 48.0f;
    const float B5 = isg ? 0.073688f  : 1.0f / 480.0f;

    // tanh(c) deg-7 odd poly on |c|<=2.1 (Chebyshev-node fit, err<=5e-3):
    const float A1 = 0.9935504f, A3 = -0.2841420f,
                A5 = 0.0606190f, A7 = -0.00535853f;

    const int tstart = seg * SEGLEN;                  // first stored t
    const int nwu = (tstart < WARMUP) ? tstart : WARMUP;  // CLAMPED warmup
    const int t0 = tstart - nwu;                      // first processed t (>=0)

    // prefetch ring: one gate scalar per lane per step; coalesced 256B/wave.
    float ring[16];
#pragma unroll
    for (int p = 0; p < 16; ++p) ring[p] = xdot[(t0 + p) * 512 + col];

    float c = 0.0f;
    float tanhc = 0.0f;    // tanh(c) carried instead of h
    float ovwl = 0.0f;     // o * wl carried; a = tanhc*ovwl + u
    float4 h4;
    float4* hout4 = (float4*)(hseq + chain * T_STEPS);  // [b][t] layout

    // ---- warmup: converge state, no stores (block-uniform trip count) ----
    for (int tb = 0; tb < nwu; tb += 16) {
#pragma unroll
        for (int j = 0; j < 16; ++j) {
            float cur = ring[j];
            ring[j] = xdot[(t0 + tb + 16 + j) * 512 + col];

            float sn = __builtin_amdgcn_sinf(fmaf(tanhc, ovwl, cur));
            float t = sn * sn;
            float snt = sn * t;
            float q = fmaf(t, B5, B3);
            float r0 = fmaf(sn, B1, B0);
            float gate = fmaf(snt, q, r0);

            float fv = quad_bcast<0>(gate);
            float iv = quad_bcast<1>(gate);
            float gv = quad_bcast<2>(gate);
            float ov = quad_bcast<3>(gate);

            c = fmaf(fv, c, iv * gv);
            ovwl = ov * wl;
            float tc  = c * c;
            float ctc = c * tc;
            float ac  = c * A1;
            float s1  = fmaf(tc, A7, A5);
            float s   = fmaf(tc, s1, A3);
            tanhc = fmaf(ctc, s, ac);
        }
    }

    // ---- main: SEGLEN stored steps; refill continues seamlessly ----
    for (int tb = 0; tb < SEGLEN; tb += 16) {
#pragma unroll
        for (int j = 0; j < 16; ++j) {
            float cur = ring[j];
            ring[j] = xdot[(tstart + tb + 16 + j) * 512 + col];  // padded past end

            float sn = __builtin_amdgcn_sinf(fmaf(tanhc, ovwl, cur));
            float t = sn * sn;
            float snt = sn * t;
            float q = fmaf(t, B5, B3);
            float r0 = fmaf(sn, B1, B0);
            float gate = fmaf(snt, q, r0);

            float fv = quad_bcast<0>(gate);
            float iv = quad_bcast<1>(gate);
            float gv = quad_bcast<2>(gate);
            float ov = quad_bcast<3>(gate);

            c = fmaf(fv, c, iv * gv);
            ovwl = ov * wl;
            float tc  = c * c;
            float ctc = c * tc;
            float ac  = c * A1;
            float s1  = fmaf(tc, A7, A5);
            float s   = fmaf(tc, s1, A3);
            tanhc = fmaf(ctc, s, ac);
            float h = ov * tanhc;               // store only

            if ((j & 3) == 0)      h4.x = h;
            else if ((j & 3) == 1) h4.y = h;
            else if ((j & 3) == 2) h4.z = h;
            else { h4.w = h; if (r == 0) hout4[(tstart + tb + j) >> 2] = h4; }
        }
    }
    if (seg == NSEG - 1 && r == 0) cfin[chain] = c;
}

// broadcast h over H=256 columns; wave per output row of 64 float4s.
// rows: [0,131072) stacked, [131072,131200) hx, [131200,131328) cx
// hseq is [b][t]-major: value for output row r=(t*128+b) is hseq[b*1024 + t].
// Output is write-once: non-temporal stores.
__global__ __launch_bounds__(256) void k_bcast(const float* __restrict__ hseq,
                                               const float* __restrict__ cfin,
                                               float4* __restrict__ out) {
    const int wave = blockIdx.x * (blockDim.x >> 6) + (threadIdx.x >> 6);
    const int lane = threadIdx.x & 63;
    const int NR = T_STEPS * B_DIM;
    if (wave >= NR + 2 * B_DIM) return;
    float v;
    if (wave < NR) {
        int t = wave >> 7, bb = wave & 127;
        v = hseq[bb * T_STEPS + t];
    } else if (wave < NR + B_DIM) {
        v = hseq[(wave - NR) * T_STEPS + (T_STEPS - 1)];
    } else {
        v = cfin[wave - NR - B_DIM];
    }
    nt_store4(&out[(size_t)wave * 64 + lane], make_float4(v, v, v, v));
}

extern "C" void kernel_launch(void* const* d_in, const int* in_sizes, int n_in,
                              void* d_out, int out_size, void* d_ws, size_t ws_size,
                              hipStream_t stream) {
    const float* x = (const float*)d_in[0];   // (1024,128,256) f32
    const float* W = (const float*)d_in[1];   // (4,512) f32
    const float* b = (const float*)d_in[2];   // (4,) f32
    // d_in[3] = qw — mathematically inert (sin invariant under RX then H)

    float* out = (float*)d_out;

    float* wsf  = (float*)d_ws;
    float* hseq = wsf + 16;                      // 131072 floats, [b][t]
    float* cfin = wsf + 16 + T_STEPS * B_DIM;    // 128 floats
    float* xdot = out;  // ~2.2 MB scratch in d_out head (incl. 16-step pad);
                        // d_out fully overwritten by k_bcast afterwards.

    k_xdot<<<2048, 256, 0, stream>>>(x, W, b, xdot);
    k_scan<<<2 * NSEG, 256, 0, stream>>>(xdot, W, hseq, cfin);

    const int rows = T_STEPS * B_DIM + 2 * B_DIM;          // 131328
    k_bcast<<<(rows + 3) / 4, 256, 0, stream>>>(hseq, cfin, (float4*)out);
}